// Round 3
// baseline (3381.021 us; speedup 1.0000x reference)
//
#include <hip/hip_runtime.h>

// Shapes (fixed by the reference)
#define BN 4
#define CN 64
#define ON 64
#define VN 163842
#define KN 7
#define JN 7
#define CJ 448      // CN*JN
#define GROUP 4     // vertices per block-iteration
#define NG ((VN + GROUP - 1) / GROUP)     // 40961
#define GRID 512
#define GPB ((NG + GRID - 1) / GRID)      // 81
#define VT_CHUNKS ((VN + 63) / 64)        // 2561

// ---------------------------------------------------------------------------
// Pass 1: transpose x[b][c][v] -> xT[b][v][c]
// ---------------------------------------------------------------------------
__launch_bounds__(256, 4)
__global__ void transpose_kernel(const float* __restrict__ x, float* __restrict__ xT) {
    __shared__ float tile[64][65];
    const int bid   = blockIdx.x;
    const int b     = bid / VT_CHUNKS;
    const int vbase = (bid % VT_CHUNKS) * 64;
    const int t     = threadIdx.x;
    const int vl    = t & 63;
    const int cr    = t >> 6;

    if (vbase + vl < VN) {
        #pragma unroll
        for (int i = 0; i < 16; ++i) {
            const int c = cr * 16 + i;
            tile[c][vl] = x[((size_t)b * CN + c) * VN + vbase + vl];
        }
    }
    __syncthreads();
    #pragma unroll
    for (int i = 0; i < 16; ++i) {
        const int vr = cr * 16 + i;
        const int v  = vbase + vr;
        if (v < VN)
            xT[((size_t)b * VN + v) * CN + (t & 63)] = tile[t & 63][vr];
    }
}

// ---------------------------------------------------------------------------
// Pass 2: fused gather+interp+conv.
// out[b,o,v] = sum_{c,j} (sum_k xT[b,idx[v,k],c] * itp[v,k,j]) * w[o,c,j] + bias[o]
//
// 512 threads = 8 waves. Main GEMM: o = lane, cq = wave (8 slices of 56 cj).
// cj slice mapping (interleaved): cj'(e,cq) -> c = 8*(e&7)+cq, j = e>>3.
// T LDS layout: dword = vi*1792 + j*256 + c*4 + (b ^ ((c>>3)&3))   [2-way writes, aligned b128 reads]
// ---------------------------------------------------------------------------
__launch_bounds__(512, 4)
__global__ void sphere_conv_v3(const float* __restrict__ xT,
                               const int* __restrict__ index,
                               const float* __restrict__ itp,
                               const float* __restrict__ w,
                               const float* __restrict__ bias,
                               float* __restrict__ out) {
    __shared__ float Tl[GROUP * 1792];          // 28,672 B
    __shared__ float red[8 * 64 * 16];          // 32,768 B

    const int t    = threadIdx.x;
    const int lane = t & 63;
    const int wv   = t >> 6;        // 0..7

    const int o  = lane;            // main-GEMM output channel
    const int cq = wv;              // cj-slice owner

    // wreg[e] = w[o, c=8*(e&7)+cq, j=e>>3]   (one-time, L2-cached)
    float wreg[56];
    #pragma unroll
    for (int e = 0; e < 56; ++e)
        wreg[e] = w[o * CJ + (8 * (e & 7) + cq) * JN + (e >> 3)];

    const int bA = wv & 3;          // phase-A batch
    const int vh = wv >> 2;         // phase-A vertex half

    const int bid = blockIdx.x;
    for (int g0 = 0; g0 < GPB; ++g0) {
        const int g = bid * GPB + g0;          // contiguous v-range per block
        if (g >= NG) break;
        const int vbase = g * GROUP;

        // ---------- phase A: build T for 4 vertices ----------
        #pragma unroll
        for (int vi2 = 0; vi2 < 2; ++vi2) {
            const int vi = vh * 2 + vi2;
            const int v  = min(vbase + vi, VN - 1);
            const int*   ip = index + v * KN;
            const float* mp = itp   + v * (KN * JN);
            float xv[KN];
            #pragma unroll
            for (int k = 0; k < KN; ++k) {
                const unsigned ik = (unsigned)ip[k];                   // uniform -> s_load
                xv[k] = xT[(unsigned)(bA * VN + ik) * CN + lane];      // coalesced 256B/wave
            }
            #pragma unroll
            for (int j = 0; j < JN; ++j) {
                float tj = 0.f;
                #pragma unroll
                for (int k = 0; k < KN; ++k) tj = fmaf(xv[k], mp[k * JN + j], tj);
                Tl[vi * 1792 + j * 256 + lane * 4 + (bA ^ ((lane >> 3) & 3))] = tj;
            }
        }
        __syncthreads();

        // ---------- main contraction: acc[vi][b] over 56 cj ----------
        float acc[GROUP][4];
        #pragma unroll
        for (int vi = 0; vi < GROUP; ++vi) {
            acc[vi][0] = 0.f; acc[vi][1] = 0.f; acc[vi][2] = 0.f; acc[vi][3] = 0.f;
        }
        #pragma unroll
        for (int e = 0; e < 56; ++e) {
            const int   base = (e >> 3) * 256 + 32 * (e & 7) + 4 * cq;  // + vi*1792
            const float we   = wreg[e];
            const int   s    = e & 3;           // compile-time b-permute
            #pragma unroll
            for (int vi = 0; vi < GROUP; ++vi) {
                const float4 tv = *reinterpret_cast<const float4*>(&Tl[vi * 1792 + base]);
                acc[vi][0 ^ s] = fmaf(tv.x, we, acc[vi][0 ^ s]);
                acc[vi][1 ^ s] = fmaf(tv.y, we, acc[vi][1 ^ s]);
                acc[vi][2 ^ s] = fmaf(tv.z, we, acc[vi][2 ^ s]);
                acc[vi][3 ^ s] = fmaf(tv.w, we, acc[vi][3 ^ s]);
            }
        }
        __syncthreads();

        // ---------- partials to LDS (slot-swizzled) ----------
        #pragma unroll
        for (int vi = 0; vi < GROUP; ++vi) {
            float4 f;
            f.x = acc[vi][0]; f.y = acc[vi][1]; f.z = acc[vi][2]; f.w = acc[vi][3];
            *reinterpret_cast<float4*>(&red[(cq * 64 + o) * 16 + (vi ^ (o & 3)) * 4]) = f;
        }
        __syncthreads();

        // ---------- sum 8 partials, add bias, store ----------
        #pragma unroll
        for (int p = 0; p < 2; ++p) {
            const int item = t + p * 512;       // 1024 outputs per group
            const int vloc = item & 3;
            const int bo   = item >> 2;         // b*64 + o
            const int oo   = bo & 63;
            const int bb   = bo >> 6;
            float s = bias[oo];
            #pragma unroll
            for (int q = 0; q < 8; ++q)
                s += red[(q * 64 + oo) * 16 + (vloc ^ (oo & 3)) * 4 + bb];
            const int vv = vbase + vloc;
            if (vv < VN) out[(unsigned)bo * VN + vv] = s;
        }
        __syncthreads();
    }
}

// ---------------------------------------------------------------------------
// Fallback (ws too small): direct strided gather, modest but correct.
// ---------------------------------------------------------------------------
__launch_bounds__(512, 4)
__global__ void sphere_conv_fb(const float* __restrict__ x,
                               const int* __restrict__ index,
                               const float* __restrict__ itp,
                               const float* __restrict__ w,
                               const float* __restrict__ bias,
                               float* __restrict__ out) {
    __shared__ float Tl[GROUP * 1792];
    __shared__ float red[8 * 64 * 16];
    const int t    = threadIdx.x;
    const int lane = t & 63;
    const int wv   = t >> 6;
    const int o  = lane;
    const int cq = wv;
    float wreg[56];
    #pragma unroll
    for (int e = 0; e < 56; ++e)
        wreg[e] = w[o * CJ + (8 * (e & 7) + cq) * JN + (e >> 3)];
    const int bA = wv & 3;
    const int vh = wv >> 2;
    const int bid = blockIdx.x;
    for (int g0 = 0; g0 < GPB; ++g0) {
        const int g = bid * GPB + g0;
        if (g >= NG) break;
        const int vbase = g * GROUP;
        #pragma unroll
        for (int vi2 = 0; vi2 < 2; ++vi2) {
            const int vi = vh * 2 + vi2;
            const int v  = min(vbase + vi, VN - 1);
            const int*   ip = index + v * KN;
            const float* mp = itp   + v * (KN * JN);
            float xv[KN];
            #pragma unroll
            for (int k = 0; k < KN; ++k)
                xv[k] = x[(size_t)(bA * CN + lane) * VN + ip[k]];   // strided gather
            #pragma unroll
            for (int j = 0; j < JN; ++j) {
                float tj = 0.f;
                #pragma unroll
                for (int k = 0; k < KN; ++k) tj = fmaf(xv[k], mp[k * JN + j], tj);
                Tl[vi * 1792 + j * 256 + lane * 4 + (bA ^ ((lane >> 3) & 3))] = tj;
            }
        }
        __syncthreads();
        float acc[GROUP][4];
        #pragma unroll
        for (int vi = 0; vi < GROUP; ++vi) {
            acc[vi][0] = 0.f; acc[vi][1] = 0.f; acc[vi][2] = 0.f; acc[vi][3] = 0.f;
        }
        #pragma unroll
        for (int e = 0; e < 56; ++e) {
            const int   base = (e >> 3) * 256 + 32 * (e & 7) + 4 * cq;
            const float we   = wreg[e];
            const int   s    = e & 3;
            #pragma unroll
            for (int vi = 0; vi < GROUP; ++vi) {
                const float4 tv = *reinterpret_cast<const float4*>(&Tl[vi * 1792 + base]);
                acc[vi][0 ^ s] = fmaf(tv.x, we, acc[vi][0 ^ s]);
                acc[vi][1 ^ s] = fmaf(tv.y, we, acc[vi][1 ^ s]);
                acc[vi][2 ^ s] = fmaf(tv.z, we, acc[vi][2 ^ s]);
                acc[vi][3 ^ s] = fmaf(tv.w, we, acc[vi][3 ^ s]);
            }
        }
        __syncthreads();
        #pragma unroll
        for (int vi = 0; vi < GROUP; ++vi) {
            float4 f;
            f.x = acc[vi][0]; f.y = acc[vi][1]; f.z = acc[vi][2]; f.w = acc[vi][3];
            *reinterpret_cast<float4*>(&red[(cq * 64 + o) * 16 + (vi ^ (o & 3)) * 4]) = f;
        }
        __syncthreads();
        #pragma unroll
        for (int p = 0; p < 2; ++p) {
            const int item = t + p * 512;
            const int vloc = item & 3;
            const int bo   = item >> 2;
            const int oo   = bo & 63;
            const int bb   = bo >> 6;
            float s = bias[oo];
            #pragma unroll
            for (int q = 0; q < 8; ++q)
                s += red[(q * 64 + oo) * 16 + (vloc ^ (oo & 3)) * 4 + bb];
            const int vv = vbase + vloc;
            if (vv < VN) out[(unsigned)bo * VN + vv] = s;
        }
        __syncthreads();
    }
}

extern "C" void kernel_launch(void* const* d_in, const int* in_sizes, int n_in,
                              void* d_out, int out_size, void* d_ws, size_t ws_size,
                              hipStream_t stream) {
    const float* x     = (const float*)d_in[0];
    const int*   index = (const int*)  d_in[1];
    const float* itp   = (const float*)d_in[2];
    const float* w     = (const float*)d_in[3];
    const float* bias  = (const float*)d_in[4];
    float*       out   = (float*)d_out;

    const size_t xt_bytes = (size_t)BN * VN * CN * sizeof(float);

    if (ws_size >= xt_bytes) {
        float* xT = (float*)d_ws;
        transpose_kernel<<<dim3(BN * VT_CHUNKS), dim3(256), 0, stream>>>(x, xT);
        sphere_conv_v3<<<dim3(GRID), dim3(512), 0, stream>>>(xT, index, itp, w, bias, out);
    } else {
        sphere_conv_fb<<<dim3(GRID), dim3(512), 0, stream>>>(x, index, itp, w, bias, out);
    }
}